// Round 1
// baseline (281.123 us; speedup 1.0000x reference)
//
#include <hip/hip_runtime.h>

// ============================================================================
// PGALoss: analytically reduced.
//   per-point loss = sqrt(1 + d^2) + d,  d = distance to nearest neighbor
//   out = 0.5 * sum_dir clip((mean_{B,N} loss - 1)/2, 0, 1)
// d^2 computed as min_m(||p||^2 - 2 q.p) + ||q||^2  (no index tracking needed)
// ============================================================================

// ws layout: [0,64): double acc[2] (per-direction sums). [64, 64+4N*16): float4
// preprocessed points {x,y,z,pp}: source occupies [0,2N), target [2N,4N).

__global__ void prep_kernel(const float* __restrict__ src,
                            const float* __restrict__ tgt,
                            float4* __restrict__ P4,
                            double* __restrict__ acc,
                            int twoN) {
    int idx = blockIdx.x * blockDim.x + threadIdx.x;
    if (idx < 2) acc[idx] = 0.0;           // zero accumulators (stream-ordered)
    int total = 2 * twoN;
    if (idx >= total) return;
    int which = idx >= twoN ? 1 : 0;        // 0 = source, 1 = target
    int i = idx - which * twoN;
    const float* in = which ? tgt : src;
    float x = in[3 * i + 0];
    float y = in[3 * i + 1];
    float z = in[3 * i + 2];
    float pp = x * x + y * y + z * z;
    P4[idx] = make_float4(x, y, z, pp);
}

#define QPB   128   // queries per block
#define PTILE 512   // points staged per iteration (2 halves x 256)

__global__ __launch_bounds__(256)
void nn_kernel(const float4* __restrict__ P4, double* __restrict__ acc, int N) {
    __shared__ float4 tile[PTILE];          // 8 KB
    __shared__ float  comb[QPB];

    const int t      = threadIdx.x;
    const int bpt    = N / QPB;             // blocks per task
    const int task   = blockIdx.x / bpt;
    const int qchunk = blockIdx.x % bpt;
    const int dir    = task & 1;            // 0: q=source,p=target  1: q=target,p=source
    const int batch  = task >> 1;
    const int twoN   = 2 * N;

    const float4* qArr = P4 + dir * twoN + batch * N;
    const float4* pArr = P4 + (1 - dir) * twoN + batch * N;

    const int qi = qchunk * QPB + (t & (QPB - 1));
    const int h  = t >> 7;                  // which half of the point tile

    float4 q4 = qArr[qi];
    const float q2x = -2.0f * q4.x;
    const float q2y = -2.0f * q4.y;
    const float q2z = -2.0f * q4.z;
    const float qq  = q4.w;

    float best = 3.4e38f;
    const int iters = N / PTILE;
    for (int it = 0; it < iters; ++it) {
        const float4* g = pArr + it * PTILE;
        tile[t]       = g[t];
        tile[t + 256] = g[t + 256];
        __syncthreads();
        const float4* tp = &tile[h * 256];
        #pragma unroll 8
        for (int j = 0; j < 256; ++j) {
            float4 p = tp[j];
            float d = fmaf(p.x, q2x, fmaf(p.y, q2y, fmaf(p.z, q2z, p.w)));
            best = fminf(best, d);
        }
        __syncthreads();
    }

    // combine the two halves (threads t and t+128 hold the same query)
    if (t >= 128) comb[t - 128] = best;
    __syncthreads();
    if (t < 128) {
        best = fminf(best, comb[t]);
        float d2 = fmaxf(best + qq, 0.0f);
        float f  = sqrtf(1.0f + d2) + sqrtf(d2);
        // wave-level reduce (64 lanes), two waves active
        for (int o = 32; o > 0; o >>= 1) f += __shfl_down(f, o);
        if ((t & 63) == 0) atomicAdd(&acc[dir], (double)f);
    }
}

__global__ void final_kernel(const double* __restrict__ acc,
                             float* __restrict__ out, int N) {
    double inv = 1.0 / (double)(2 * N);     // mean over B*N = 2N elements
    double l0 = (acc[0] * inv - 1.0) * 0.5;
    double l1 = (acc[1] * inv - 1.0) * 0.5;
    l0 = l0 < 0.0 ? 0.0 : (l0 > 1.0 ? 1.0 : l0);
    l1 = l1 < 0.0 ? 0.0 : (l1 > 1.0 ? 1.0 : l1);
    out[0] = (float)(0.5 * (l0 + l1));
}

extern "C" void kernel_launch(void* const* d_in, const int* in_sizes, int n_in,
                              void* d_out, int out_size, void* d_ws, size_t ws_size,
                              hipStream_t stream) {
    const float* src = (const float*)d_in[0];
    const float* tgt = (const float*)d_in[1];
    float* out = (float*)d_out;

    const int twoN = in_sizes[0] / 3;       // B*N with B=2  -> 16384
    const int N    = twoN / 2;              // 8192

    double* acc = (double*)d_ws;
    float4* P4  = (float4*)((char*)d_ws + 64);

    const int totalPts = 2 * twoN;
    prep_kernel<<<(totalPts + 255) / 256, 256, 0, stream>>>(src, tgt, P4, acc, twoN);

    const int blocksPerTask = N / QPB;      // 64
    nn_kernel<<<4 * blocksPerTask, 256, 0, stream>>>(P4, acc, N);

    final_kernel<<<1, 1, 0, stream>>>(acc, out, N);
}

// Round 2
// 44.488 us; speedup vs baseline: 6.3191x; 6.3191x over previous
//
#include <hip/hip_runtime.h>

// ============================================================================
// PGALoss, analytically reduced:
//   per-point loss = sqrt(1 + d^2) + d,  d = NN distance
//   out = 0.5 * sum_dir clip((mean loss - 1)/2, 0, 1)
// d^2 = min_m(||p||^2 - 2 q.p) + ||q||^2
//
// R2: register-tile Q=4 queries/thread (ILP: 4 independent min chains,
// 16 VALU per LDS broadcast read), split points PS ways for occupancy,
// deterministic partial-min buffer + separate reduce kernel.
// ============================================================================

// ws layout:
//   [0,64)                    : double acc[2]
//   [64, 64+16*4N)            : float4 P4[4N]  {x,y,z,||p||^2}, src then tgt
//   [64+16*4N, ... )          : float partial[PS][4N]

#define TPB  256
#define Q    4
#define TILE 1024   // float4 entries staged per LDS pass (16 KB)

__global__ void prep_kernel(const float* __restrict__ src,
                            const float* __restrict__ tgt,
                            float4* __restrict__ P4,
                            double* __restrict__ acc,
                            int twoN) {
    int idx = blockIdx.x * blockDim.x + threadIdx.x;
    if (idx < 2) acc[idx] = 0.0;
    int total = 2 * twoN;
    if (idx >= total) return;
    int which = idx >= twoN ? 1 : 0;
    int i = idx - which * twoN;
    const float* in = which ? tgt : src;
    float x = in[3 * i + 0];
    float y = in[3 * i + 1];
    float z = in[3 * i + 2];
    P4[idx] = make_float4(x, y, z, x * x + y * y + z * z);
}

__global__ __launch_bounds__(TPB)
void nn_kernel(const float4* __restrict__ P4, float* __restrict__ partial,
               int N, int PS) {
    __shared__ float4 tile[TILE];

    const int t    = threadIdx.x;
    const int QPB  = TPB * Q;            // queries per block (1024)
    const int bpt  = (N / QPB) * PS;     // blocks per task
    const int task = blockIdx.x / bpt;
    const int rem  = blockIdx.x % bpt;
    const int qc   = rem / PS;           // query chunk
    const int pc   = rem % PS;           // point chunk
    const int dir  = task >> 1;
    const int batch= task & 1;
    const int twoN = 2 * N;
    const int ppb  = N / PS;             // points per block

    const float4* qArr = P4 + dir * twoN + batch * N + qc * QPB;
    const float4* pArr = P4 + (1 - dir) * twoN + batch * N + pc * ppb;

    float qx[Q], qy[Q], qz[Q], best[Q];
    #pragma unroll
    for (int k = 0; k < Q; ++k) {
        float4 q = qArr[t + k * TPB];
        qx[k] = -2.0f * q.x;
        qy[k] = -2.0f * q.y;
        qz[k] = -2.0f * q.z;
        best[k] = 3.4e38f;
    }

    for (int base = 0; base < ppb; base += TILE) {
        const int cnt = min(TILE, ppb - base);
        __syncthreads();                      // protect previous tile
        for (int i = t; i < cnt; i += TPB) tile[i] = pArr[base + i];
        __syncthreads();
        #pragma unroll 4
        for (int j = 0; j < cnt; ++j) {
            float4 p = tile[j];               // broadcast read, conflict-free
            #pragma unroll
            for (int k = 0; k < Q; ++k)
                best[k] = fminf(best[k],
                    fmaf(p.x, qx[k], fmaf(p.y, qy[k], fmaf(p.z, qz[k], p.w))));
        }
    }

    const int QT = 4 * N;
    const int gqBase = task * N + qc * QPB;
    #pragma unroll
    for (int k = 0; k < Q; ++k)
        partial[(size_t)pc * QT + gqBase + k * TPB + t] = best[k];
}

__global__ __launch_bounds__(256)
void reduce_kernel(const float4* __restrict__ P4, const float* __restrict__ partial,
                   double* __restrict__ acc, int N, int PS) {
    const int gq = blockIdx.x * 256 + threadIdx.x;   // == P4 linear index
    const int QT = 4 * N;
    float best = 3.4e38f;
    for (int ps = 0; ps < PS; ++ps)
        best = fminf(best, partial[(size_t)ps * QT + gq]);
    float d2 = fmaxf(best + P4[gq].w, 0.0f);
    float f  = sqrtf(1.0f + d2) + sqrtf(d2);
    for (int o = 32; o > 0; o >>= 1) f += __shfl_down(f, o);
    const int dir = gq / (2 * N);                    // wave-uniform (2N % 64 == 0)
    if ((threadIdx.x & 63) == 0) atomicAdd(&acc[dir], (double)f);
}

__global__ void final_kernel(const double* __restrict__ acc,
                             float* __restrict__ out, int N) {
    double inv = 1.0 / (double)(2 * N);
    double l0 = (acc[0] * inv - 1.0) * 0.5;
    double l1 = (acc[1] * inv - 1.0) * 0.5;
    l0 = l0 < 0.0 ? 0.0 : (l0 > 1.0 ? 1.0 : l0);
    l1 = l1 < 0.0 ? 0.0 : (l1 > 1.0 ? 1.0 : l1);
    out[0] = (float)(0.5 * (l0 + l1));
}

extern "C" void kernel_launch(void* const* d_in, const int* in_sizes, int n_in,
                              void* d_out, int out_size, void* d_ws, size_t ws_size,
                              hipStream_t stream) {
    const float* src = (const float*)d_in[0];
    const float* tgt = (const float*)d_in[1];
    float* out = (float*)d_out;

    const int twoN = in_sizes[0] / 3;    // 16384
    const int N    = twoN / 2;           // 8192
    const int QT   = 4 * N;              // 32768 total queries

    double* acc    = (double*)d_ws;
    float4* P4     = (float4*)((char*)d_ws + 64);
    float* partial = (float*)((char*)d_ws + 64 + (size_t)2 * twoN * sizeof(float4));

    // pick largest point-split that fits the workspace
    size_t fixed = 64 + (size_t)2 * twoN * sizeof(float4);
    int PS = 16;
    while (PS > 1 && fixed + (size_t)PS * QT * sizeof(float) > ws_size) PS >>= 1;

    const int totalPts = 2 * twoN;
    prep_kernel<<<(totalPts + 255) / 256, 256, 0, stream>>>(src, tgt, P4, acc, twoN);

    const int blocks = 4 * (N / (TPB * Q)) * PS;     // 512 at PS=16
    nn_kernel<<<blocks, TPB, 0, stream>>>(P4, partial, N, PS);

    reduce_kernel<<<QT / 256, 256, 0, stream>>>(P4, partial, acc, N, PS);

    final_kernel<<<1, 1, 0, stream>>>(acc, out, N);
}

// Round 3
// 42.859 us; speedup vs baseline: 6.5592x; 1.0380x over previous
//
#include <hip/hip_runtime.h>

// ============================================================================
// PGALoss, analytically reduced:
//   per-point loss = sqrt(1 + d^2) + d,  d = NN distance
//   out = 0.5 * sum_dir clip((mean loss - 1)/2, 0, 1)
// d^2 = min_m(||p||^2 - 2 q.p) + ||q||^2
//
// R3: no prep kernel (pp computed during LDS staging, qq recomputed in
// reduce). Q=8 queries/thread (32 VALU per LDS broadcast -> LDS port no
// longer the limit; 8 independent min chains). Point pairs + min3.
// PS-way point split, deterministic partial buffer, 3 kernels total.
// ============================================================================

// ws layout:
//   [0,64)   : double acc[2]
//   [64, ...): float partial[PS][QT],  QT = 4*N total queries

#define TPB  256
#define Q    8
#define TILE 1024   // max float4 entries staged (16 KB LDS)

__global__ __launch_bounds__(TPB)
void nn_kernel(const float* __restrict__ src, const float* __restrict__ tgt,
               float* __restrict__ partial, double* __restrict__ acc,
               int N, int PS) {
    __shared__ float4 tile[TILE];

    const int t = threadIdx.x;
    if (blockIdx.x == 0 && t < 2) acc[t] = 0.0;   // zero accumulators

    const int QPB  = TPB * Q;            // queries per block (2048)
    const int nqc  = N / QPB;            // query chunks per task (4)
    const int bpt  = nqc * PS;           // blocks per task
    const int task = blockIdx.x / bpt;
    const int rem  = blockIdx.x % bpt;
    const int qc   = rem / PS;
    const int pc   = rem % PS;
    const int dir  = task >> 1;          // 0: q=source,p=target
    const int batch= task & 1;
    const int ppb  = N / PS;             // points per block

    const float* qRaw = (dir ? tgt : src) + (size_t)3 * (batch * N + qc * QPB);
    const float* pRaw = (dir ? src : tgt) + (size_t)3 * (batch * N + pc * ppb);

    float qx[Q], qy[Q], qz[Q], best[Q];
    #pragma unroll
    for (int k = 0; k < Q; ++k) {
        const float* qr = qRaw + 3 * (k * TPB + t);
        qx[k] = -2.0f * qr[0];
        qy[k] = -2.0f * qr[1];
        qz[k] = -2.0f * qr[2];
        best[k] = 3.4e38f;
    }

    for (int base = 0; base < ppb; base += TILE) {
        const int cnt = min(TILE, ppb - base);
        __syncthreads();
        for (int i = t; i < cnt; i += TPB) {
            const float* pr = pRaw + 3 * (base + i);
            float x = pr[0], y = pr[1], z = pr[2];
            tile[i] = make_float4(x, y, z, x * x + y * y + z * z);
        }
        __syncthreads();
        for (int j = 0; j < cnt; j += 2) {
            float4 p0 = tile[j];
            float4 p1 = tile[j + 1];
            #pragma unroll
            for (int k = 0; k < Q; ++k) {
                float d0 = fmaf(p0.x, qx[k], fmaf(p0.y, qy[k], fmaf(p0.z, qz[k], p0.w)));
                float d1 = fmaf(p1.x, qx[k], fmaf(p1.y, qy[k], fmaf(p1.z, qz[k], p1.w)));
                best[k] = fminf(fminf(d0, d1), best[k]);   // -> v_min3_f32
            }
        }
    }

    const int QT = 4 * N;
    float* dst = partial + (size_t)pc * QT + task * N + qc * QPB + t;
    #pragma unroll
    for (int k = 0; k < Q; ++k) dst[k * TPB] = best[k];
}

__global__ __launch_bounds__(256)
void reduce_kernel(const float* __restrict__ src, const float* __restrict__ tgt,
                   const float* __restrict__ partial, double* __restrict__ acc,
                   int N, int PS) {
    const int gq = blockIdx.x * 256 + threadIdx.x;   // [0, 4N)
    const int QT = 4 * N;
    float best = 3.4e38f;
    for (int ps = 0; ps < PS; ++ps)
        best = fminf(best, partial[(size_t)ps * QT + gq]);

    const int dir = gq / (2 * N);                    // wave-uniform
    const int ci  = gq & (2 * N - 1);                // index within query cloud
    const float* qr = (dir ? tgt : src) + (size_t)3 * ci;
    float qq = qr[0] * qr[0] + qr[1] * qr[1] + qr[2] * qr[2];

    float d2 = fmaxf(best + qq, 0.0f);
    float f  = sqrtf(1.0f + d2) + sqrtf(d2);
    for (int o = 32; o > 0; o >>= 1) f += __shfl_down(f, o);
    if ((threadIdx.x & 63) == 0) atomicAdd(&acc[dir], (double)f);
}

__global__ void final_kernel(const double* __restrict__ acc,
                             float* __restrict__ out, int N) {
    double inv = 1.0 / (double)(2 * N);
    double l0 = (acc[0] * inv - 1.0) * 0.5;
    double l1 = (acc[1] * inv - 1.0) * 0.5;
    l0 = l0 < 0.0 ? 0.0 : (l0 > 1.0 ? 1.0 : l0);
    l1 = l1 < 0.0 ? 0.0 : (l1 > 1.0 ? 1.0 : l1);
    out[0] = (float)(0.5 * (l0 + l1));
}

extern "C" void kernel_launch(void* const* d_in, const int* in_sizes, int n_in,
                              void* d_out, int out_size, void* d_ws, size_t ws_size,
                              hipStream_t stream) {
    const float* src = (const float*)d_in[0];
    const float* tgt = (const float*)d_in[1];
    float* out = (float*)d_out;

    const int twoN = in_sizes[0] / 3;    // 16384
    const int N    = twoN / 2;           // 8192
    const int QT   = 4 * N;              // 32768

    double* acc    = (double*)d_ws;
    float* partial = (float*)((char*)d_ws + 64);

    int PS = 32;                          // point-split; 512 blocks at PS=32
    while (PS > 1 && 64 + (size_t)PS * QT * sizeof(float) > ws_size) PS >>= 1;

    const int blocks = 4 * (N / (TPB * Q)) * PS;
    nn_kernel<<<blocks, TPB, 0, stream>>>(src, tgt, partial, acc, N, PS);

    reduce_kernel<<<QT / 256, 256, 0, stream>>>(src, tgt, partial, acc, N, PS);

    final_kernel<<<1, 1, 0, stream>>>(acc, out, N);
}

// Round 4
// 41.555 us; speedup vs baseline: 6.7650x; 1.0314x over previous
//
#include <hip/hip_runtime.h>

// ============================================================================
// PGALoss, analytically reduced:
//   per-point loss = sqrt(1 + d^2) + d,  d = NN distance
//   out = 0.5 * sum_dir clip((mean loss - 1)/2, 0, 1)
// d^2 = min_m(||p||^2 - 2 q.p) + ||q||^2
//
// R4: packed-f32 math (v_pk_fma_f32): LDS holds point PAIRS SoA-style
// ({x0,x1,y0,y1},{z0,z1,w0,w1}); 6 pk_fma + 2 min3 per 4 points per query
// = 2.0 VALU/pair (was 3.5). Partial-min buffer replaced by uint atomicMin
// (d^2 >= 0 so float bit order == numeric order; min is order-independent).
// Final transform folded into reduce via last-block counter.
// ============================================================================

typedef float v2f __attribute__((ext_vector_type(2)));

#define TPB 256
#define Q   4     // queries per thread

// ws layout:
//   [0,16)  : double acc[2]
//   [32,36) : uint counter
//   [64, 64+4*QT): uint partialMin[QT]   (init 0x7f7f7f7f = 3.39e38)

__global__ __launch_bounds__(TPB)
void nn_kernel(const float* __restrict__ src, const float* __restrict__ tgt,
               unsigned int* __restrict__ partialMin, int N, int PS) {
    __shared__ float4 tileA[1024];   // {x0,x1,y0,y1} per point-pair
    __shared__ float4 tileB[1024];   // {z0,z1,w0,w1}

    const int t    = threadIdx.x;
    const int QPB  = TPB * Q;            // 1024 queries per block
    const int nqc  = N / QPB;
    const int bpt  = nqc * PS;
    const int task = blockIdx.x / bpt;   // dir = task>>1, batch = task&1
    const int rem  = blockIdx.x % bpt;
    const int qc   = rem / PS;
    const int pc   = rem % PS;
    const int dir  = task >> 1;
    const int batch= task & 1;
    const int ppb  = N / PS;             // points per block
    const int npairs = ppb / 2;

    const float* qRaw = (dir ? tgt : src) + (size_t)3 * (batch * N + qc * QPB);
    const float* pRaw = (dir ? src : tgt) + (size_t)3 * (batch * N + pc * ppb);

    v2f qx2[Q], qy2[Q], qz2[Q];
    float qq[Q], best0[Q], best1[Q];
    #pragma unroll
    for (int k = 0; k < Q; ++k) {
        const float* qr = qRaw + 3 * (k * TPB + t);
        float x = qr[0], y = qr[1], z = qr[2];
        qx2[k] = (v2f){-2.0f * x, -2.0f * x};
        qy2[k] = (v2f){-2.0f * y, -2.0f * y};
        qz2[k] = (v2f){-2.0f * z, -2.0f * z};
        qq[k]  = x * x + y * y + z * z;
        best0[k] = 3.4e38f;
        best1[k] = 3.4e38f;
    }

    for (int i = t; i < npairs; i += TPB) {
        const float* pr = pRaw + 6 * i;
        float x0 = pr[0], y0 = pr[1], z0 = pr[2];
        float x1 = pr[3], y1 = pr[4], z1 = pr[5];
        tileA[i] = make_float4(x0, x1, y0, y1);
        tileB[i] = make_float4(z0, z1,
                               x0 * x0 + y0 * y0 + z0 * z0,
                               x1 * x1 + y1 * y1 + z1 * z1);
    }
    __syncthreads();

    #pragma unroll 4
    for (int j = 0; j < npairs; j += 2) {
        float4 a0 = tileA[j],     b0 = tileB[j];
        float4 a1 = tileA[j + 1], b1 = tileB[j + 1];
        v2f x0 = (v2f){a0.x, a0.y}, y0v = (v2f){a0.z, a0.w};
        v2f z0v = (v2f){b0.x, b0.y}, w0 = (v2f){b0.z, b0.w};
        v2f x1 = (v2f){a1.x, a1.y}, y1v = (v2f){a1.z, a1.w};
        v2f z1v = (v2f){b1.x, b1.y}, w1 = (v2f){b1.z, b1.w};
        #pragma unroll
        for (int k = 0; k < Q; ++k) {
            v2f d0 = __builtin_elementwise_fma(x0, qx2[k],
                     __builtin_elementwise_fma(y0v, qy2[k],
                     __builtin_elementwise_fma(z0v, qz2[k], w0)));
            v2f d1 = __builtin_elementwise_fma(x1, qx2[k],
                     __builtin_elementwise_fma(y1v, qy2[k],
                     __builtin_elementwise_fma(z1v, qz2[k], w1)));
            best0[k] = fminf(fminf(d0.x, d1.x), best0[k]);  // v_min3_f32
            best1[k] = fminf(fminf(d0.y, d1.y), best1[k]);
        }
    }

    const int gqBase = task * N + qc * QPB + t;
    #pragma unroll
    for (int k = 0; k < Q; ++k) {
        float best = fminf(best0[k], best1[k]);
        float d2 = fmaxf(best + qq[k], 0.0f);
        atomicMin(&partialMin[gqBase + k * TPB], __float_as_uint(d2));
    }
}

__global__ __launch_bounds__(256)
void reduce_kernel(const unsigned int* __restrict__ partialMin,
                   double* __restrict__ acc, unsigned int* __restrict__ counter,
                   float* __restrict__ out, int N) {
    const int gq = blockIdx.x * 256 + threadIdx.x;
    float d2 = __uint_as_float(partialMin[gq]);
    float f  = sqrtf(1.0f + d2) + sqrtf(d2);
    for (int o = 32; o > 0; o >>= 1) f += __shfl_down(f, o);
    const int dir = gq / (2 * N);                    // wave-uniform
    if ((threadIdx.x & 63) == 0) atomicAdd(&acc[dir], (double)f);
    __syncthreads();
    if (threadIdx.x == 0) {
        __threadfence();
        unsigned int old = atomicAdd(counter, 1u);
        if (old == gridDim.x - 1) {                  // last block finishes
            double s0 = atomicAdd(&acc[0], 0.0);     // coherent reads
            double s1 = atomicAdd(&acc[1], 0.0);
            double inv = 1.0 / (double)(2 * N);
            double l0 = (s0 * inv - 1.0) * 0.5;
            double l1 = (s1 * inv - 1.0) * 0.5;
            l0 = l0 < 0.0 ? 0.0 : (l0 > 1.0 ? 1.0 : l0);
            l1 = l1 < 0.0 ? 0.0 : (l1 > 1.0 ? 1.0 : l1);
            out[0] = (float)(0.5 * (l0 + l1));
        }
    }
}

extern "C" void kernel_launch(void* const* d_in, const int* in_sizes, int n_in,
                              void* d_out, int out_size, void* d_ws, size_t ws_size,
                              hipStream_t stream) {
    const float* src = (const float*)d_in[0];
    const float* tgt = (const float*)d_in[1];
    float* out = (float*)d_out;

    const int twoN = in_sizes[0] / 3;    // 16384
    const int N    = twoN / 2;           // 8192
    const int QT   = 4 * N;              // 32768

    double* acc          = (double*)d_ws;
    unsigned int* counter= (unsigned int*)((char*)d_ws + 32);
    unsigned int* pmin   = (unsigned int*)((char*)d_ws + 64);

    hipMemsetAsync(d_ws, 0, 64, stream);                       // acc + counter
    hipMemsetAsync(pmin, 0x7f, (size_t)QT * sizeof(unsigned int), stream); // +3.39e38

    int PS = 32;
    while (PS > 1 && (N / PS) % 4 != 0) PS >>= 1;

    const int blocks = 4 * (N / (TPB * Q)) * PS;   // 1024
    nn_kernel<<<blocks, TPB, 0, stream>>>(src, tgt, pmin, N, PS);

    reduce_kernel<<<QT / 256, 256, 0, stream>>>(pmin, acc, counter, out, N);
}